// Round 22
// baseline (546.768 us; speedup 1.0000x reference)
//
#include <hip/hip_runtime.h>
#include <hip/hip_bf16.h>
#include <stdint.h>

#define R_TOT   131072
#define D_IN    1024
#define N_CLS   81
#define N_BOX   320
#define N_H     256
#define N1_USED 657
#define N1_PAD  768   // padded to 2 panels x 384 (8 waves x 48); cols 657..767 are zero
#define NB_COLS 384   // per-block N panel

typedef __attribute__((ext_vector_type(8))) short short8;
typedef __attribute__((ext_vector_type(4))) float f32x4;

__device__ __forceinline__ unsigned short f2bf(float f) {
  union { float f; unsigned u; } v; v.f = f;
  unsigned r = v.u + 0x7FFFu + ((v.u >> 16) & 1u);
  return (unsigned short)(r >> 16);
}

__device__ __forceinline__ short8 cvt8(float4 a, float4 b) {
  short8 v;
  v[0] = (short)f2bf(a.x); v[1] = (short)f2bf(a.y);
  v[2] = (short)f2bf(a.z); v[3] = (short)f2bf(a.w);
  v[4] = (short)f2bf(b.x); v[5] = (short)f2bf(b.y);
  v[6] = (short)f2bf(b.z); v[7] = (short)f2bf(b.w);
  return v;
}

__device__ __forceinline__ void async_lds16(void* lds, const void* g) {
  __builtin_amdgcn_global_load_lds(
      (const __attribute__((address_space(1))) unsigned int*)g,
      (__attribute__((address_space(3))) unsigned int*)lds, 16, 0, 0);
}

// ---------------- prep: pack W_big into K-panels [32][768][32] bf16 (zero-padded) ----
__global__ void prep_w1(const float* __restrict__ Wc, const float* __restrict__ Wb,
                        const float* __restrict__ W1, unsigned short* __restrict__ Wp)
{
  int idx = blockIdx.x * 256 + threadIdx.x;      // < 768*1024
  int p   = idx / (N1_PAD * 32);
  int rem = idx % (N1_PAD * 32);
  int n   = rem >> 5;
  int kk  = rem & 31;
  int k   = p * 32 + kk;
  float w = 0.f;
  if (n < N_CLS)               w = Wc[(size_t)n * D_IN + k];
  else if (n < N_CLS + N_BOX)  w = Wb[(size_t)(n - N_CLS) * D_IN + k];
  else if (n < N1_USED)        w = W1[(size_t)(n - (N_CLS + N_BOX)) * D_IN + k];
  Wp[idx] = f2bf(w);                             // cols >= 657 stay 0
}

__global__ void prep_w23(const float* __restrict__ W2, const float* __restrict__ W3,
                         unsigned short* __restrict__ W2b, unsigned short* __restrict__ W3b)
{
  int idx = blockIdx.x * 256 + threadIdx.x;      // < 131072
  if (idx < 65536) W2b[idx] = f2bf(W2[idx]);
  else             W3b[idx - 65536] = f2bf(W3[idx - 65536]);
}

// ---------------- GEMM1: 64(M) x 384(N) per block, K=1024 ----------------
// Grid 4096 = 2048 M-tiles x 2 N-panels; bijective XCD swizzle; 512 thr / 8 waves,
// wave owns 64x48, acc[4][3] (R18's proven FLOP-density point: 12 MFMA per
// 4 A-reads + 3 B-loads; R21 proved higher occupancy at lower density LOSES).
// B: direct global->reg from L2-resident Wp, depth-1 prefetch (R14/R18).
// R22 change: A staged as fp32 via ASYNC global_load_lds (R12/R13's proven
// pre-swizzled-source path), chunk [64][128] fp32 = 32 KB x 2 buffers.
// Next chunk's DMA is issued at the TOP of the current chunk (4 steps ~1100cyc
// cover >> 900cyc HBM); fp32->bf16 conversion at fragment-read (v_cvt_pk).
// This deletes R18's synchronous chunk-boundary burst (global reads + 16 cvt +
// 4 ds_write under the barrier) -- zero VALU, zero reg spike at the boundary.
// One barrier per 4 K-steps. LDS 64 KB -> 2 blocks/CU (= the 16-wave reg cap).
__global__ __launch_bounds__(512) void g1_kernel(
    const float* __restrict__ x, const unsigned short* __restrict__ Wp,
    const float* __restrict__ b_cls, const float* __restrict__ b_box,
    const float* __restrict__ b1,
    float* __restrict__ scores, float* __restrict__ deltas,
    unsigned short* __restrict__ h1)
{
  __shared__ __attribute__((aligned(16))) float As[2][64 * 128];  // 2 x 32 KB

  const int tid  = threadIdx.x;
  const int wave = tid >> 6;
  const int lane = tid & 63;
  // bijective XCD-chunk swizzle (nwg = 4096, 4096 % 8 == 0)
  const int orig  = blockIdx.x;
  const int work  = (orig & 7) * 512 + (orig >> 3);
  const int m0    = (work >> 1) * 64;
  const int nbase = (work & 1) * NB_COLS;

  const int lr  = lane & 15;
  const int hig = lane >> 4;          // 0..3

  f32x4 acc[4][3];
#pragma unroll
  for (int i = 0; i < 4; ++i)
#pragma unroll
    for (int j = 0; j < 3; ++j)
      acc[i][j] = (f32x4){0.f, 0.f, 0.f, 0.f};

  // Async A staging: chunk c covers k in [c*128, c*128+128). 2048 16-B slots;
  // LDS dest is LINEAR (byte = idx*16 -> wave-uniform base + lane*16, m104-safe);
  // the swizzle lives in the per-lane GLOBAL source address (m173 pattern):
  // LDS[row][slot s] holds global k-quad (s ^ (row&7)) of that row.
  auto stageA = [&](int buf, int c) {
#pragma unroll
    for (int i = 0; i < 4; ++i) {
      int idx = tid + i * 512;
      int row = idx >> 5, s = idx & 31;
      const float* src = x + (size_t)(m0 + row) * D_IN + c * 128 + ((s ^ (row & 7)) << 2);
      async_lds16((char*)&As[buf][0] + idx * 16, src);
    }
  };

  // per-lane B fragment pointer: col = nbase + wave*48 + lr, k-octet hig*8.
  const unsigned short* bptr = Wp + (size_t)(nbase + wave * 48 + lr) * 32 + hig * 8;
  const size_t BSTEP = (size_t)N1_PAD * 32;

  stageA(0, 0);
  short8 bCur0 = *(const short8*)(bptr);
  short8 bCur1 = *(const short8*)(bptr + 512);
  short8 bCur2 = *(const short8*)(bptr + 1024);
  bptr += BSTEP;
  __syncthreads();                    // chunk 0 + bCur resident

  union U8 { unsigned u[4]; short8 s; };

#pragma unroll 4
  for (int kp = 0; kp < 32; ++kp) {
    const int c   = kp >> 2;
    const int sub = kp & 3;
    const int cur = c & 1;

    // top of chunk: issue next chunk's DMA into the freed buffer
    if (sub == 0 && c + 1 < 8) stageA(cur ^ 1, c + 1);

    // B depth-1 prefetch (stays in flight across the MFMAs)
    short8 bn0, bn1, bn2;
    if (kp < 31) {
      bn0 = *(const short8*)(bptr);
      bn1 = *(const short8*)(bptr + 512);
      bn2 = *(const short8*)(bptr + 1024);
      bptr += BSTEP;
    }

    // compute: per mi, 2 swizzled fp32 b128 reads -> cvt_pk -> 3 MFMAs
    const int s0 = sub * 8 + hig * 2;              // first k-quad of this lane's octet
#pragma unroll
    for (int mi = 0; mi < 4; ++mi) {
      const int r = mi * 16 + lr;
      const char* Ab = (const char*)&As[cur][0] + r * 512;
      float4 p0 = *(const float4*)(Ab + (((s0    ) ^ (r & 7)) << 4));
      float4 p1 = *(const float4*)(Ab + (((s0 + 1) ^ (r & 7)) << 4));
      U8 t;
      asm("v_cvt_pk_bf16_f32 %0, %1, %2" : "=v"(t.u[0]) : "v"(p0.x), "v"(p0.y));
      asm("v_cvt_pk_bf16_f32 %0, %1, %2" : "=v"(t.u[1]) : "v"(p0.z), "v"(p0.w));
      asm("v_cvt_pk_bf16_f32 %0, %1, %2" : "=v"(t.u[2]) : "v"(p1.x), "v"(p1.y));
      asm("v_cvt_pk_bf16_f32 %0, %1, %2" : "=v"(t.u[3]) : "v"(p1.z), "v"(p1.w));
      short8 af = t.s;
      acc[mi][0] = __builtin_amdgcn_mfma_f32_16x16x32_bf16(af, bCur0, acc[mi][0], 0, 0, 0);
      acc[mi][1] = __builtin_amdgcn_mfma_f32_16x16x32_bf16(af, bCur1, acc[mi][1], 0, 0, 0);
      acc[mi][2] = __builtin_amdgcn_mfma_f32_16x16x32_bf16(af, bCur2, acc[mi][2], 0, 0, 0);
    }

    if (kp < 31) { bCur0 = bn0; bCur1 = bn1; bCur2 = bn2; }

    // end of chunk: reads of As[cur] done; next chunk's DMA (issued 4 steps
    // ago) is drained by the implicit vmcnt(0) here -- fully covered.
    if (sub == 3 && kp < 31) __syncthreads();
  }

  // ---- epilogue: split cols into scores / deltas / h1 (cols >= 657 skipped) ----
  const int rbase = m0 + (hig << 2);
#pragma unroll
  for (int mi = 0; mi < 4; ++mi) {
#pragma unroll
    for (int ni = 0; ni < 3; ++ni) {
      int n = nbase + wave * 48 + ni * 16 + lr;
      if (n >= N1_USED) continue;
      if (n < N_CLS) {
        float bb = b_cls[n];
#pragma unroll
        for (int j = 0; j < 4; ++j) {
          int r = rbase + mi * 16 + j;
          scores[(size_t)r * N_CLS + n] = acc[mi][ni][j] + bb;
        }
      } else if (n < N_CLS + N_BOX) {
        int nb = n - N_CLS;
        float bb = b_box[nb];
#pragma unroll
        for (int j = 0; j < 4; ++j) {
          int r = rbase + mi * 16 + j;
          deltas[(size_t)r * N_BOX + nb] = acc[mi][ni][j] + bb;
        }
      } else {
        int nh = n - (N_CLS + N_BOX);
        float bb = b1[nh];
#pragma unroll
        for (int j = 0; j < 4; ++j) {
          int r = rbase + mi * 16 + j;
          float h = acc[mi][ni][j] + bb;
          h1[(size_t)r * N_H + nh] = f2bf(fmaxf(h, 0.f));
        }
      }
    }
  }
}

// ---------------- GEMM2/3: full-row blocks, 128(M) x 256(N=all), K=256, BK=32 ----
// 512 threads (8 waves), wave (wm,wn) = (wave>>2, wave&3), per-wave 64x64 output.
// Each block reads ONLY A rows [m0,m0+128) and writes ONLY those rows ->
// in-place (out==A) is block-local and race-free. Grid is (R/128, 1).
__device__ __forceinline__ void g23_stage(unsigned short* Asb, unsigned short* Bsb,
    const unsigned short* __restrict__ A, const unsigned short* __restrict__ Bw,
    int m0, int kp, int tid)
{
  {
    int row = tid >> 2, kq = tid & 3;             // A: 512 chunks of 16B
    async_lds16((char*)Asb + tid * 16,
                (const char*)(A + (size_t)(m0 + row) * N_H + (size_t)kp * 32 + kq * 8));
  }
#pragma unroll
  for (int i = 0; i < 2; ++i) {                   // B: 1024 chunks of 16B
    int chunk = tid + i * 512;
    int row = chunk >> 2, kq = chunk & 3;
    async_lds16((char*)Bsb + chunk * 16,
                (const char*)(Bw + (size_t)row * N_H + (size_t)kp * 32 + kq * 8));
  }
}

template <int RELU, int OUT_BF16>
__global__ __launch_bounds__(512, 1) void g23_kernel(
    const unsigned short* __restrict__ A, const unsigned short* __restrict__ Bw,
    const float* __restrict__ bias, void* __restrict__ outv)
{
  __shared__ __attribute__((aligned(16))) unsigned short As[2][128 * 32];
  __shared__ __attribute__((aligned(16))) unsigned short Bs[2][256 * 32];
  const int tid  = threadIdx.x;
  const int wave = tid >> 6, lane = tid & 63;
  const int wm = wave >> 2, wn = wave & 3;
  const int m0 = blockIdx.x * 128;

  f32x4 acc[4][4];
#pragma unroll
  for (int i = 0; i < 4; ++i)
#pragma unroll
    for (int j = 0; j < 4; ++j)
      acc[i][j] = (f32x4){0.f, 0.f, 0.f, 0.f};

  g23_stage(&As[0][0], &Bs[0][0], A, Bw, m0, 0, tid);
  __syncthreads();

  const int lr = lane & 15;
  const int lk = (lane >> 4) * 8;

  for (int kp = 0; kp < 8; ++kp) {
    const int cur = kp & 1, nxt = cur ^ 1;
    if (kp < 7) g23_stage(&As[nxt][0], &Bs[nxt][0], A, Bw, m0, kp + 1, tid);

    short8 af[4], bfr[4];
#pragma unroll
    for (int mi = 0; mi < 4; ++mi)
      af[mi] = *(const short8*)&As[cur][(wm * 64 + mi * 16 + lr) * 32 + lk];
#pragma unroll
    for (int ni = 0; ni < 4; ++ni)
      bfr[ni] = *(const short8*)&Bs[cur][(wn * 64 + ni * 16 + lr) * 32 + lk];
#pragma unroll
    for (int mi = 0; mi < 4; ++mi)
#pragma unroll
      for (int ni = 0; ni < 4; ++ni)
        acc[mi][ni] = __builtin_amdgcn_mfma_f32_16x16x32_bf16(af[mi], bfr[ni], acc[mi][ni], 0, 0, 0);
    __syncthreads();
  }

  // All LDS reads of A done; safe to overwrite our own rows (even if out==A).
#pragma unroll
  for (int mi = 0; mi < 4; ++mi) {
#pragma unroll
    for (int ni = 0; ni < 4; ++ni) {
      int n = wn * 64 + ni * 16 + lr;
      float bb = bias[n];
#pragma unroll
      for (int j = 0; j < 4; ++j) {
        int r = m0 + wm * 64 + mi * 16 + ((lane >> 4) << 2) + j;
        float v = acc[mi][ni][j] + bb;
        if (RELU) v = fmaxf(v, 0.f);
        if (OUT_BF16) ((unsigned short*)outv)[(size_t)r * N_H + n] = f2bf(v);
        else          ((float*)outv)[(size_t)r * N_H + n] = v;
      }
    }
  }
}

// ---------------- launch ----------------
extern "C" void kernel_launch(void* const* d_in, const int* in_sizes, int n_in,
                              void* d_out, int out_size, void* d_ws, size_t ws_size,
                              hipStream_t stream)
{
  const float* x     = (const float*)d_in[0];
  const float* W_cls = (const float*)d_in[1];
  const float* b_cls = (const float*)d_in[2];
  const float* W_box = (const float*)d_in[3];
  const float* b_box = (const float*)d_in[4];
  const float* W1    = (const float*)d_in[5];
  const float* b1    = (const float*)d_in[6];
  const float* W2    = (const float*)d_in[7];
  const float* b2    = (const float*)d_in[8];
  const float* W3    = (const float*)d_in[9];
  const float* b3    = (const float*)d_in[10];

  float* scores = (float*)d_out;
  float* deltas = scores + (size_t)R_TOT * N_CLS;
  float* embeds = deltas + (size_t)R_TOT * N_BOX;

  // Scratch layout (total ~68.9 MB):
  //   Wp  : 768*1024 bf16      = 1,572,864 B   (zero-padded K-panel layout)
  //   W2b :  65536 bf16        =   131,072 B
  //   W3b :  65536 bf16        =   131,072 B
  //   h   : 131072*256 bf16    = 67,108,864 B  (h1; GEMM2 overwrites in place -> h2)
  char* ws = (char*)d_ws;
  unsigned short* Wp  = (unsigned short*)ws;
  unsigned short* W2b = (unsigned short*)(ws + 1572864);
  unsigned short* W3b = (unsigned short*)(ws + 1572864 + 131072);
  unsigned short* h   = (unsigned short*)(ws + 1835008);

  hipLaunchKernelGGL(prep_w1, dim3(3072), dim3(256), 0, stream, W_cls, W_box, W1, Wp);
  hipLaunchKernelGGL(prep_w23, dim3(512), dim3(256), 0, stream, W2, W3, W2b, W3b);
  hipLaunchKernelGGL(g1_kernel, dim3(4096), dim3(512), 0, stream,
                     x, Wp, b_cls, b_box, b1, scores, deltas, h);
  hipLaunchKernelGGL((g23_kernel<1, 1>), dim3(R_TOT / 128), dim3(512), 0, stream,
                     h, W2b, b2, (void*)h);       // in place: h1 -> h2 (block-local rows)
  hipLaunchKernelGGL((g23_kernel<0, 0>), dim3(R_TOT / 128), dim3(512), 0, stream,
                     h, W3b, b3, (void*)embeds);
}

// Round 23
// 428.328 us; speedup vs baseline: 1.2765x; 1.2765x over previous
//
#include <hip/hip_runtime.h>
#include <hip/hip_bf16.h>
#include <stdint.h>

#define R_TOT   131072
#define D_IN    1024
#define N_CLS   81
#define N_BOX   320
#define N_H     256
#define N1_USED 657
#define N1_PAD  768   // padded to 2 panels x 384 (8 waves x 48); cols 657..767 are zero
#define NB_COLS 384   // per-block N panel

typedef __attribute__((ext_vector_type(8))) short short8;
typedef __attribute__((ext_vector_type(4))) float f32x4;

__device__ __forceinline__ unsigned short f2bf(float f) {
  union { float f; unsigned u; } v; v.f = f;
  unsigned r = v.u + 0x7FFFu + ((v.u >> 16) & 1u);
  return (unsigned short)(r >> 16);
}

__device__ __forceinline__ short8 cvt8(float4 a, float4 b) {
  short8 v;
  v[0] = (short)f2bf(a.x); v[1] = (short)f2bf(a.y);
  v[2] = (short)f2bf(a.z); v[3] = (short)f2bf(a.w);
  v[4] = (short)f2bf(b.x); v[5] = (short)f2bf(b.y);
  v[6] = (short)f2bf(b.z); v[7] = (short)f2bf(b.w);
  return v;
}

__device__ __forceinline__ void async_lds16(void* lds, const void* g) {
  __builtin_amdgcn_global_load_lds(
      (const __attribute__((address_space(1))) unsigned int*)g,
      (__attribute__((address_space(3))) unsigned int*)lds, 16, 0, 0);
}

// ---------------- prep: pack W_big into K-panels [32][768][32] bf16 (zero-padded) ----
__global__ void prep_w1(const float* __restrict__ Wc, const float* __restrict__ Wb,
                        const float* __restrict__ W1, unsigned short* __restrict__ Wp)
{
  int idx = blockIdx.x * 256 + threadIdx.x;      // < 768*1024
  int p   = idx / (N1_PAD * 32);
  int rem = idx % (N1_PAD * 32);
  int n   = rem >> 5;
  int kk  = rem & 31;
  int k   = p * 32 + kk;
  float w = 0.f;
  if (n < N_CLS)               w = Wc[(size_t)n * D_IN + k];
  else if (n < N_CLS + N_BOX)  w = Wb[(size_t)(n - N_CLS) * D_IN + k];
  else if (n < N1_USED)        w = W1[(size_t)(n - (N_CLS + N_BOX)) * D_IN + k];
  Wp[idx] = f2bf(w);                             // cols >= 657 stay 0
}

__global__ void prep_w23(const float* __restrict__ W2, const float* __restrict__ W3,
                         unsigned short* __restrict__ W2b, unsigned short* __restrict__ W3b)
{
  int idx = blockIdx.x * 256 + threadIdx.x;      // < 131072
  if (idx < 65536) W2b[idx] = f2bf(W2[idx]);
  else             W3b[idx - 65536] = f2bf(W3[idx - 65536]);
}

// ---------------- GEMM1: 64(M) x 384(N) per block, K=1024 ----------------
// R23 = R18-EXACT (best known: g1 378 us, VGPR 52, occ 43%) + s_setprio(1/0)
// around the MFMA cluster (zero-reg, zero-LDS, zero-structure lever; R18 runs
// ~1.6 staggered blocks/CU so arbitration may pay; null expected, bounded).
// Campaign state: R19/R20/R21/R22 all regressed via the same mechanism --
// any added registers or LDS collapses co-residency, which outweighs ILP.
// Grid 4096 = 2048 M-tiles x 2 N-panels; bijective XCD swizzle; 512 thr / 8 waves,
// wave owns 64x48, acc[4][3]. B: direct global->reg from L2-resident Wp,
// depth-1 prefetch. A: single 32 KB bf16 chunk [64][256] staged every 8 steps
// (burst at boundary), XOR-swizzled slot^(row&7).
__global__ __launch_bounds__(512) void g1_kernel(
    const float* __restrict__ x, const unsigned short* __restrict__ Wp,
    const float* __restrict__ b_cls, const float* __restrict__ b_box,
    const float* __restrict__ b1,
    float* __restrict__ scores, float* __restrict__ deltas,
    unsigned short* __restrict__ h1)
{
  __shared__ __attribute__((aligned(16))) unsigned short As[64 * 256];  // 32 KB

  const int tid  = threadIdx.x;
  const int wave = tid >> 6;
  const int lane = tid & 63;
  // bijective XCD-chunk swizzle (nwg = 4096, 4096 % 8 == 0)
  const int orig  = blockIdx.x;
  const int work  = (orig & 7) * 512 + (orig >> 3);
  const int m0    = (work >> 1) * 64;
  const int nbase = (work & 1) * NB_COLS;

  const int lr  = lane & 15;
  const int hig = lane >> 4;          // 0..3
  const int g2  = hig * 8;            // k-octet element offset

  f32x4 acc[4][3];
#pragma unroll
  for (int i = 0; i < 4; ++i)
#pragma unroll
    for (int j = 0; j < 3; ++j)
      acc[i][j] = (f32x4){0.f, 0.f, 0.f, 0.f};

  // per-lane B fragment pointer: col = nbase + wave*48 + lr, k-octet g2.
  const unsigned short* bptr = Wp + (size_t)(nbase + wave * 48 + lr) * 32 + g2;
  const size_t BSTEP = (size_t)N1_PAD * 32;

  short8 bCur0 = *(const short8*)(bptr);
  short8 bCur1 = *(const short8*)(bptr + 512);
  short8 bCur2 = *(const short8*)(bptr + 1024);
  bptr += BSTEP;

#pragma unroll 2
  for (int kp = 0; kp < 32; ++kp) {
    const int kk = kp & 7;

    // ---- chunk staging every 8 steps: A[64][256] bf16, swizzled ----
    if (kk == 0) {
      if (kp > 0) __syncthreads();                 // all reads of prev chunk done
      const int c0 = (kp >> 3) * 256;              // chunk k-base
#pragma unroll
      for (int i = 0; i < 4; ++i) {                // 2048 slots = 4*512 exactly
        int idx = tid + i * 512;
        int row = idx >> 5, s = idx & 31;
        const float* src = x + (size_t)(m0 + row) * D_IN + c0 + s * 8;
        float4 f0 = *(const float4*)src;
        float4 f1 = *(const float4*)(src + 4);
        *(short8*)&As[row * 256 + ((s ^ (row & 7)) << 3)] = cvt8(f0, f1);
      }
      __syncthreads();
    }

    // ---- B prefetch for next step (stays in flight across the MFMAs) ----
    short8 bn0, bn1, bn2;
    if (kp < 31) {
      bn0 = *(const short8*)(bptr);
      bn1 = *(const short8*)(bptr + 512);
      bn2 = *(const short8*)(bptr + 1024);
      bptr += BSTEP;
    }

    // ---- compute: per mi, swizzled A-frag read then its 3 MFMAs ----
    const int sb = kk * 4 + hig;                   // base slot for this lane
    __builtin_amdgcn_s_setprio(1);
#pragma unroll
    for (int mi = 0; mi < 4; ++mi) {
      const int r  = mi * 16 + lr;
      const int sl = sb ^ (r & 7);
      short8 af = *(const short8*)&As[r * 256 + (sl << 3)];
      acc[mi][0] = __builtin_amdgcn_mfma_f32_16x16x32_bf16(af, bCur0, acc[mi][0], 0, 0, 0);
      acc[mi][1] = __builtin_amdgcn_mfma_f32_16x16x32_bf16(af, bCur1, acc[mi][1], 0, 0, 0);
      acc[mi][2] = __builtin_amdgcn_mfma_f32_16x16x32_bf16(af, bCur2, acc[mi][2], 0, 0, 0);
    }
    __builtin_amdgcn_s_setprio(0);

    if (kp < 31) { bCur0 = bn0; bCur1 = bn1; bCur2 = bn2; }
  }

  // ---- epilogue: split cols into scores / deltas / h1 (cols >= 657 skipped) ----
  const int rbase = m0 + (hig << 2);
#pragma unroll
  for (int mi = 0; mi < 4; ++mi) {
#pragma unroll
    for (int ni = 0; ni < 3; ++ni) {
      int n = nbase + wave * 48 + ni * 16 + lr;
      if (n >= N1_USED) continue;
      if (n < N_CLS) {
        float bb = b_cls[n];
#pragma unroll
        for (int j = 0; j < 4; ++j) {
          int r = rbase + mi * 16 + j;
          scores[(size_t)r * N_CLS + n] = acc[mi][ni][j] + bb;
        }
      } else if (n < N_CLS + N_BOX) {
        int nb = n - N_CLS;
        float bb = b_box[nb];
#pragma unroll
        for (int j = 0; j < 4; ++j) {
          int r = rbase + mi * 16 + j;
          deltas[(size_t)r * N_BOX + nb] = acc[mi][ni][j] + bb;
        }
      } else {
        int nh = n - (N_CLS + N_BOX);
        float bb = b1[nh];
#pragma unroll
        for (int j = 0; j < 4; ++j) {
          int r = rbase + mi * 16 + j;
          float h = acc[mi][ni][j] + bb;
          h1[(size_t)r * N_H + nh] = f2bf(fmaxf(h, 0.f));
        }
      }
    }
  }
}

// ---------------- GEMM2/3: full-row blocks, 128(M) x 256(N=all), K=256, BK=32 ----
// 512 threads (8 waves), wave (wm,wn) = (wave>>2, wave&3), per-wave 64x64 output.
// Each block reads ONLY A rows [m0,m0+128) and writes ONLY those rows ->
// in-place (out==A) is block-local and race-free. Grid is (R/128, 1).
__device__ __forceinline__ void g23_stage(unsigned short* Asb, unsigned short* Bsb,
    const unsigned short* __restrict__ A, const unsigned short* __restrict__ Bw,
    int m0, int kp, int tid)
{
  {
    int row = tid >> 2, kq = tid & 3;             // A: 512 chunks of 16B
    async_lds16((char*)Asb + tid * 16,
                (const char*)(A + (size_t)(m0 + row) * N_H + (size_t)kp * 32 + kq * 8));
  }
#pragma unroll
  for (int i = 0; i < 2; ++i) {                   // B: 1024 chunks of 16B
    int chunk = tid + i * 512;
    int row = chunk >> 2, kq = chunk & 3;
    async_lds16((char*)Bsb + chunk * 16,
                (const char*)(Bw + (size_t)row * N_H + (size_t)kp * 32 + kq * 8));
  }
}

template <int RELU, int OUT_BF16>
__global__ __launch_bounds__(512, 1) void g23_kernel(
    const unsigned short* __restrict__ A, const unsigned short* __restrict__ Bw,
    const float* __restrict__ bias, void* __restrict__ outv)
{
  __shared__ __attribute__((aligned(16))) unsigned short As[2][128 * 32];
  __shared__ __attribute__((aligned(16))) unsigned short Bs[2][256 * 32];
  const int tid  = threadIdx.x;
  const int wave = tid >> 6, lane = tid & 63;
  const int wm = wave >> 2, wn = wave & 3;
  const int m0 = blockIdx.x * 128;

  f32x4 acc[4][4];
#pragma unroll
  for (int i = 0; i < 4; ++i)
#pragma unroll
    for (int j = 0; j < 4; ++j)
      acc[i][j] = (f32x4){0.f, 0.f, 0.f, 0.f};

  g23_stage(&As[0][0], &Bs[0][0], A, Bw, m0, 0, tid);
  __syncthreads();

  const int lr = lane & 15;
  const int lk = (lane >> 4) * 8;

  for (int kp = 0; kp < 8; ++kp) {
    const int cur = kp & 1, nxt = cur ^ 1;
    if (kp < 7) g23_stage(&As[nxt][0], &Bs[nxt][0], A, Bw, m0, kp + 1, tid);

    short8 af[4], bfr[4];
#pragma unroll
    for (int mi = 0; mi < 4; ++mi)
      af[mi] = *(const short8*)&As[cur][(wm * 64 + mi * 16 + lr) * 32 + lk];
#pragma unroll
    for (int ni = 0; ni < 4; ++ni)
      bfr[ni] = *(const short8*)&Bs[cur][(wn * 64 + ni * 16 + lr) * 32 + lk];
#pragma unroll
    for (int mi = 0; mi < 4; ++mi)
#pragma unroll
      for (int ni = 0; ni < 4; ++ni)
        acc[mi][ni] = __builtin_amdgcn_mfma_f32_16x16x32_bf16(af[mi], bfr[ni], acc[mi][ni], 0, 0, 0);
    __syncthreads();
  }

  // All LDS reads of A done; safe to overwrite our own rows (even if out==A).
#pragma unroll
  for (int mi = 0; mi < 4; ++mi) {
#pragma unroll
    for (int ni = 0; ni < 4; ++ni) {
      int n = wn * 64 + ni * 16 + lr;
      float bb = bias[n];
#pragma unroll
      for (int j = 0; j < 4; ++j) {
        int r = m0 + wm * 64 + mi * 16 + ((lane >> 4) << 2) + j;
        float v = acc[mi][ni][j] + bb;
        if (RELU) v = fmaxf(v, 0.f);
        if (OUT_BF16) ((unsigned short*)outv)[(size_t)r * N_H + n] = f2bf(v);
        else          ((float*)outv)[(size_t)r * N_H + n] = v;
      }
    }
  }
}

// ---------------- launch ----------------
extern "C" void kernel_launch(void* const* d_in, const int* in_sizes, int n_in,
                              void* d_out, int out_size, void* d_ws, size_t ws_size,
                              hipStream_t stream)
{
  const float* x     = (const float*)d_in[0];
  const float* W_cls = (const float*)d_in[1];
  const float* b_cls = (const float*)d_in[2];
  const float* W_box = (const float*)d_in[3];
  const float* b_box = (const float*)d_in[4];
  const float* W1    = (const float*)d_in[5];
  const float* b1    = (const float*)d_in[6];
  const float* W2    = (const float*)d_in[7];
  const float* b2    = (const float*)d_in[8];
  const float* W3    = (const float*)d_in[9];
  const float* b3    = (const float*)d_in[10];

  float* scores = (float*)d_out;
  float* deltas = scores + (size_t)R_TOT * N_CLS;
  float* embeds = deltas + (size_t)R_TOT * N_BOX;

  // Scratch layout (total ~68.9 MB):
  //   Wp  : 768*1024 bf16      = 1,572,864 B   (zero-padded K-panel layout)
  //   W2b :  65536 bf16        =   131,072 B
  //   W3b :  65536 bf16        =   131,072 B
  //   h   : 131072*256 bf16    = 67,108,864 B  (h1; GEMM2 overwrites in place -> h2)
  char* ws = (char*)d_ws;
  unsigned short* Wp  = (unsigned short*)ws;
  unsigned short* W2b = (unsigned short*)(ws + 1572864);
  unsigned short* W3b = (unsigned short*)(ws + 1572864 + 131072);
  unsigned short* h   = (unsigned short*)(ws + 1835008);

  hipLaunchKernelGGL(prep_w1, dim3(3072), dim3(256), 0, stream, W_cls, W_box, W1, Wp);
  hipLaunchKernelGGL(prep_w23, dim3(512), dim3(256), 0, stream, W2, W3, W2b, W3b);
  hipLaunchKernelGGL(g1_kernel, dim3(4096), dim3(512), 0, stream,
                     x, Wp, b_cls, b_box, b1, scores, deltas, h);
  hipLaunchKernelGGL((g23_kernel<1, 1>), dim3(R_TOT / 128), dim3(512), 0, stream,
                     h, W2b, b2, (void*)h);       // in place: h1 -> h2 (block-local rows)
  hipLaunchKernelGGL((g23_kernel<0, 0>), dim3(R_TOT / 128), dim3(512), 0, stream,
                     h, W3b, b3, (void*)embeds);
}

// Round 24
// 416.894 us; speedup vs baseline: 1.3115x; 1.0274x over previous
//
#include <hip/hip_runtime.h>
#include <hip/hip_bf16.h>
#include <stdint.h>

#define R_TOT   131072
#define D_IN    1024
#define N_CLS   81
#define N_BOX   320
#define N_H     256
#define N1_USED 657
#define N1_PAD  768   // padded to 2 panels x 384 (8 waves x 48); cols 657..767 are zero
#define NB_COLS 384   // per-block N panel

typedef __attribute__((ext_vector_type(8))) short short8;
typedef __attribute__((ext_vector_type(4))) float f32x4;

__device__ __forceinline__ unsigned short f2bf(float f) {
  union { float f; unsigned u; } v; v.f = f;
  unsigned r = v.u + 0x7FFFu + ((v.u >> 16) & 1u);
  return (unsigned short)(r >> 16);
}

__device__ __forceinline__ short8 cvt8(float4 a, float4 b) {
  short8 v;
  v[0] = (short)f2bf(a.x); v[1] = (short)f2bf(a.y);
  v[2] = (short)f2bf(a.z); v[3] = (short)f2bf(a.w);
  v[4] = (short)f2bf(b.x); v[5] = (short)f2bf(b.y);
  v[6] = (short)f2bf(b.z); v[7] = (short)f2bf(b.w);
  return v;
}

__device__ __forceinline__ void async_lds16(void* lds, const void* g) {
  __builtin_amdgcn_global_load_lds(
      (const __attribute__((address_space(1))) unsigned int*)g,
      (__attribute__((address_space(3))) unsigned int*)lds, 16, 0, 0);
}

// ---------------- prep: pack W_big into K-panels [32][768][32] bf16 (zero-padded) ----
__global__ void prep_w1(const float* __restrict__ Wc, const float* __restrict__ Wb,
                        const float* __restrict__ W1, unsigned short* __restrict__ Wp)
{
  int idx = blockIdx.x * 256 + threadIdx.x;      // < 768*1024
  int p   = idx / (N1_PAD * 32);
  int rem = idx % (N1_PAD * 32);
  int n   = rem >> 5;
  int kk  = rem & 31;
  int k   = p * 32 + kk;
  float w = 0.f;
  if (n < N_CLS)               w = Wc[(size_t)n * D_IN + k];
  else if (n < N_CLS + N_BOX)  w = Wb[(size_t)(n - N_CLS) * D_IN + k];
  else if (n < N1_USED)        w = W1[(size_t)(n - (N_CLS + N_BOX)) * D_IN + k];
  Wp[idx] = f2bf(w);                             // cols >= 657 stay 0
}

__global__ void prep_w23(const float* __restrict__ W2, const float* __restrict__ W3,
                         unsigned short* __restrict__ W2b, unsigned short* __restrict__ W3b)
{
  int idx = blockIdx.x * 256 + threadIdx.x;      // < 131072
  if (idx < 65536) W2b[idx] = f2bf(W2[idx]);
  else             W3b[idx - 65536] = f2bf(W3[idx - 65536]);
}

// ---------------- GEMM1: 64(M) x 384(N) per block, K=1024 (R23-exact, banked) ----
// g1 = 377 us, VGPR 52, occ 43% -- confirmed local optimum (R19-R22 all lost
// via register/LDS-occupancy tax; counted-vmcnt R13 and setprio R23 null).
__global__ __launch_bounds__(512) void g1_kernel(
    const float* __restrict__ x, const unsigned short* __restrict__ Wp,
    const float* __restrict__ b_cls, const float* __restrict__ b_box,
    const float* __restrict__ b1,
    float* __restrict__ scores, float* __restrict__ deltas,
    unsigned short* __restrict__ h1)
{
  __shared__ __attribute__((aligned(16))) unsigned short As[64 * 256];  // 32 KB

  const int tid  = threadIdx.x;
  const int wave = tid >> 6;
  const int lane = tid & 63;
  const int orig  = blockIdx.x;
  const int work  = (orig & 7) * 512 + (orig >> 3);
  const int m0    = (work >> 1) * 64;
  const int nbase = (work & 1) * NB_COLS;

  const int lr  = lane & 15;
  const int hig = lane >> 4;
  const int g2  = hig * 8;

  f32x4 acc[4][3];
#pragma unroll
  for (int i = 0; i < 4; ++i)
#pragma unroll
    for (int j = 0; j < 3; ++j)
      acc[i][j] = (f32x4){0.f, 0.f, 0.f, 0.f};

  const unsigned short* bptr = Wp + (size_t)(nbase + wave * 48 + lr) * 32 + g2;
  const size_t BSTEP = (size_t)N1_PAD * 32;

  short8 bCur0 = *(const short8*)(bptr);
  short8 bCur1 = *(const short8*)(bptr + 512);
  short8 bCur2 = *(const short8*)(bptr + 1024);
  bptr += BSTEP;

#pragma unroll 2
  for (int kp = 0; kp < 32; ++kp) {
    const int kk = kp & 7;

    if (kk == 0) {
      if (kp > 0) __syncthreads();
      const int c0 = (kp >> 3) * 256;
#pragma unroll
      for (int i = 0; i < 4; ++i) {
        int idx = tid + i * 512;
        int row = idx >> 5, s = idx & 31;
        const float* src = x + (size_t)(m0 + row) * D_IN + c0 + s * 8;
        float4 f0 = *(const float4*)src;
        float4 f1 = *(const float4*)(src + 4);
        *(short8*)&As[row * 256 + ((s ^ (row & 7)) << 3)] = cvt8(f0, f1);
      }
      __syncthreads();
    }

    short8 bn0, bn1, bn2;
    if (kp < 31) {
      bn0 = *(const short8*)(bptr);
      bn1 = *(const short8*)(bptr + 512);
      bn2 = *(const short8*)(bptr + 1024);
      bptr += BSTEP;
    }

    const int sb = kk * 4 + hig;
    __builtin_amdgcn_s_setprio(1);
#pragma unroll
    for (int mi = 0; mi < 4; ++mi) {
      const int r  = mi * 16 + lr;
      const int sl = sb ^ (r & 7);
      short8 af = *(const short8*)&As[r * 256 + (sl << 3)];
      acc[mi][0] = __builtin_amdgcn_mfma_f32_16x16x32_bf16(af, bCur0, acc[mi][0], 0, 0, 0);
      acc[mi][1] = __builtin_amdgcn_mfma_f32_16x16x32_bf16(af, bCur1, acc[mi][1], 0, 0, 0);
      acc[mi][2] = __builtin_amdgcn_mfma_f32_16x16x32_bf16(af, bCur2, acc[mi][2], 0, 0, 0);
    }
    __builtin_amdgcn_s_setprio(0);

    if (kp < 31) { bCur0 = bn0; bCur1 = bn1; bCur2 = bn2; }
  }

  const int rbase = m0 + (hig << 2);
#pragma unroll
  for (int mi = 0; mi < 4; ++mi) {
#pragma unroll
    for (int ni = 0; ni < 3; ++ni) {
      int n = nbase + wave * 48 + ni * 16 + lr;
      if (n >= N1_USED) continue;
      if (n < N_CLS) {
        float bb = b_cls[n];
#pragma unroll
        for (int j = 0; j < 4; ++j) {
          int r = rbase + mi * 16 + j;
          scores[(size_t)r * N_CLS + n] = acc[mi][ni][j] + bb;
        }
      } else if (n < N_CLS + N_BOX) {
        int nb = n - N_CLS;
        float bb = b_box[nb];
#pragma unroll
        for (int j = 0; j < 4; ++j) {
          int r = rbase + mi * 16 + j;
          deltas[(size_t)r * N_BOX + nb] = acc[mi][ni][j] + bb;
        }
      } else {
        int nh = n - (N_CLS + N_BOX);
        float bb = b1[nh];
#pragma unroll
        for (int j = 0; j < 4; ++j) {
          int r = rbase + mi * 16 + j;
          float h = acc[mi][ni][j] + bb;
          h1[(size_t)r * N_H + nh] = f2bf(fmaxf(h, 0.f));
        }
      }
    }
  }
}

// ---------------- FUSED GEMM2+GEMM3: 128(M) x 256(N), K=256 each ----------------
// R24: one kernel, block owns 128 rows end-to-end. GEMM2's relu output goes to
// a 64 KB LDS buffer H2 (XOR-swizzled 16B slots, slot^(row&7)) instead of HBM;
// GEMM3 reads its A-frags straight from H2 (2-way conflict-free) and stages
// only W3b. Deletes the 128 MB h round-trip (~20 us) + one launch.
// LDS 16+32+64 = 112 KB -> 1 block/CU; grid 1024; memory-bound tail.
__device__ __forceinline__ void gf_stageA(unsigned short* Asb,
    const unsigned short* __restrict__ A, int m0, int kp, int tid)
{
  int row = tid >> 2, kq = tid & 3;               // 512 chunks of 16B
  async_lds16((char*)Asb + tid * 16,
              (const char*)(A + (size_t)(m0 + row) * N_H + (size_t)kp * 32 + kq * 8));
}
__device__ __forceinline__ void gf_stageB(unsigned short* Bsb,
    const unsigned short* __restrict__ Bw, int kp, int tid)
{
#pragma unroll
  for (int i = 0; i < 2; ++i) {                   // 1024 chunks of 16B
    int chunk = tid + i * 512;
    int row = chunk >> 2, kq = chunk & 3;
    async_lds16((char*)Bsb + chunk * 16,
                (const char*)(Bw + (size_t)row * N_H + (size_t)kp * 32 + kq * 8));
  }
}

__global__ __launch_bounds__(512, 1) void g23_fused(
    const unsigned short* __restrict__ h1, const unsigned short* __restrict__ W2b,
    const unsigned short* __restrict__ W3b, const float* __restrict__ b2,
    const float* __restrict__ b3, float* __restrict__ embeds)
{
  __shared__ __attribute__((aligned(16))) unsigned short As[2][128 * 32];  // 16 KB
  __shared__ __attribute__((aligned(16))) unsigned short Bs[2][256 * 32];  // 32 KB
  __shared__ __attribute__((aligned(16))) unsigned short H2[128 * 256];    // 64 KB

  const int tid  = threadIdx.x;
  const int wave = tid >> 6, lane = tid & 63;
  const int wm = wave >> 2, wn = wave & 3;
  const int m0 = blockIdx.x * 128;
  const int lr = lane & 15;
  const int hig = lane >> 4;
  const int lk = hig * 8;

  f32x4 acc[4][4];
#pragma unroll
  for (int i = 0; i < 4; ++i)
#pragma unroll
    for (int j = 0; j < 4; ++j)
      acc[i][j] = (f32x4){0.f, 0.f, 0.f, 0.f};

  // ================= phase 1: h2 = relu(h1 @ W2^T + b2) -> LDS =================
  gf_stageA(&As[0][0], h1, m0, 0, tid);
  gf_stageB(&Bs[0][0], W2b, 0, tid);
  __syncthreads();

  for (int kp = 0; kp < 8; ++kp) {
    const int cur = kp & 1, nxt = cur ^ 1;
    if (kp < 7) { gf_stageA(&As[nxt][0], h1, m0, kp + 1, tid);
                  gf_stageB(&Bs[nxt][0], W2b, kp + 1, tid); }

    short8 af[4], bfr[4];
#pragma unroll
    for (int mi = 0; mi < 4; ++mi)
      af[mi] = *(const short8*)&As[cur][(wm * 64 + mi * 16 + lr) * 32 + lk];
#pragma unroll
    for (int ni = 0; ni < 4; ++ni)
      bfr[ni] = *(const short8*)&Bs[cur][(wn * 64 + ni * 16 + lr) * 32 + lk];
#pragma unroll
    for (int mi = 0; mi < 4; ++mi)
#pragma unroll
      for (int ni = 0; ni < 4; ++ni)
        acc[mi][ni] = __builtin_amdgcn_mfma_f32_16x16x32_bf16(af[mi], bfr[ni], acc[mi][ni], 0, 0, 0);
    __syncthreads();
  }

  // epilogue 1: relu + bias -> H2 (swizzled 16B slots: slot = (n>>3)^(r&7))
#pragma unroll
  for (int mi = 0; mi < 4; ++mi) {
#pragma unroll
    for (int ni = 0; ni < 4; ++ni) {
      int n = wn * 64 + ni * 16 + lr;
      float bb = b2[n];
#pragma unroll
      for (int j = 0; j < 4; ++j) {
        int r = wm * 64 + mi * 16 + (hig << 2) + j;     // local row 0..127
        float v = fmaxf(acc[mi][ni][j] + bb, 0.f);
        H2[r * 256 + (((n >> 3) ^ (r & 7)) << 3) + (n & 7)] = f2bf(v);
      }
      acc[mi][ni] = (f32x4){0.f, 0.f, 0.f, 0.f};        // re-zero for phase 2
    }
  }
  __syncthreads();

  // ================= phase 2: embeds = h2 @ W3^T + b3 ==========================
  gf_stageB(&Bs[0][0], W3b, 0, tid);
  __syncthreads();

  for (int kp = 0; kp < 8; ++kp) {
    const int cur = kp & 1, nxt = cur ^ 1;
    if (kp < 7) gf_stageB(&Bs[nxt][0], W3b, kp + 1, tid);

    short8 af[4], bfr[4];
#pragma unroll
    for (int mi = 0; mi < 4; ++mi) {
      const int r  = wm * 64 + mi * 16 + lr;
      const int co = kp * 4 + hig;                      // k-octet index 0..31
      af[mi] = *(const short8*)&H2[r * 256 + ((co ^ (r & 7)) << 3)];
    }
#pragma unroll
    for (int ni = 0; ni < 4; ++ni)
      bfr[ni] = *(const short8*)&Bs[cur][(wn * 64 + ni * 16 + lr) * 32 + lk];
#pragma unroll
    for (int mi = 0; mi < 4; ++mi)
#pragma unroll
      for (int ni = 0; ni < 4; ++ni)
        acc[mi][ni] = __builtin_amdgcn_mfma_f32_16x16x32_bf16(af[mi], bfr[ni], acc[mi][ni], 0, 0, 0);
    __syncthreads();
  }

  // epilogue 2: + b3 -> embeds (fp32)
#pragma unroll
  for (int mi = 0; mi < 4; ++mi) {
#pragma unroll
    for (int ni = 0; ni < 4; ++ni) {
      int n = wn * 64 + ni * 16 + lr;
      float bb = b3[n];
#pragma unroll
      for (int j = 0; j < 4; ++j) {
        int r = m0 + wm * 64 + mi * 16 + (hig << 2) + j;
        embeds[(size_t)r * N_H + n] = acc[mi][ni][j] + bb;
      }
    }
  }
}

// ---------------- launch ----------------
extern "C" void kernel_launch(void* const* d_in, const int* in_sizes, int n_in,
                              void* d_out, int out_size, void* d_ws, size_t ws_size,
                              hipStream_t stream)
{
  const float* x     = (const float*)d_in[0];
  const float* W_cls = (const float*)d_in[1];
  const float* b_cls = (const float*)d_in[2];
  const float* W_box = (const float*)d_in[3];
  const float* b_box = (const float*)d_in[4];
  const float* W1    = (const float*)d_in[5];
  const float* b1    = (const float*)d_in[6];
  const float* W2    = (const float*)d_in[7];
  const float* b2    = (const float*)d_in[8];
  const float* W3    = (const float*)d_in[9];
  const float* b3    = (const float*)d_in[10];

  float* scores = (float*)d_out;
  float* deltas = scores + (size_t)R_TOT * N_CLS;
  float* embeds = deltas + (size_t)R_TOT * N_BOX;

  // Scratch layout (total ~68.9 MB):
  //   Wp  : 768*1024 bf16      = 1,572,864 B   (zero-padded K-panel layout)
  //   W2b :  65536 bf16        =   131,072 B
  //   W3b :  65536 bf16        =   131,072 B
  //   h1  : 131072*256 bf16    = 67,108,864 B  (read-only after g1; h2 lives in LDS)
  char* ws = (char*)d_ws;
  unsigned short* Wp  = (unsigned short*)ws;
  unsigned short* W2b = (unsigned short*)(ws + 1572864);
  unsigned short* W3b = (unsigned short*)(ws + 1572864 + 131072);
  unsigned short* h1  = (unsigned short*)(ws + 1835008);

  hipLaunchKernelGGL(prep_w1, dim3(3072), dim3(256), 0, stream, W_cls, W_box, W1, Wp);
  hipLaunchKernelGGL(prep_w23, dim3(512), dim3(256), 0, stream, W2, W3, W2b, W3b);
  hipLaunchKernelGGL(g1_kernel, dim3(4096), dim3(512), 0, stream,
                     x, Wp, b_cls, b_box, b1, scores, deltas, h1);
  hipLaunchKernelGGL(g23_fused, dim3(R_TOT / 128), dim3(512), 0, stream,
                     h1, W2b, W3b, b2, b3, embeds);
}